// Round 18
// baseline (729.843 us; speedup 1.0000x reference)
//
#include <hip/hip_runtime.h>
#include <hip/hip_bf16.h>
#include <stdint.h>

typedef float    f32x4  __attribute__((ext_vector_type(4)));
typedef __bf16   bf16x8 __attribute__((ext_vector_type(8)));
typedef _Float16 f16x8  __attribute__((ext_vector_type(8)));
typedef _Float16 h2v    __attribute__((ext_vector_type(2)));

#define B_ 32
#define S_ 128
#define T_ 128
#define H_ 256
#define E_ 256
#define V_ 32000

// ---------- async global->LDS (16B per lane) ----------
__device__ __forceinline__ void gll16(const void* g, void* l) {
  __builtin_amdgcn_global_load_lds(
      (const __attribute__((address_space(1))) uint32_t*)g,
      (__attribute__((address_space(3))) uint32_t*)l,
      16, 0, 0);
}

__device__ __forceinline__ uint32_t pack_pair(float a, float b) {
  unsigned short lo = __builtin_bit_cast(unsigned short, (_Float16)a);
  unsigned short hi = __builtin_bit_cast(unsigned short, (_Float16)b);
  return (uint32_t)lo | ((uint32_t)hi << 16);
}

__device__ __forceinline__ uint32_t pack_bf16(float a, float b) {
  return (uint32_t)__builtin_bit_cast(unsigned short, __float2bfloat16(a)) |
         ((uint32_t)__builtin_bit_cast(unsigned short, __float2bfloat16(b)) << 16);
}

__device__ __forceinline__ float dot2(uint32_t w, uint32_t h, float acc) {
#if __has_builtin(__builtin_amdgcn_fdot2)
  return __builtin_amdgcn_fdot2(__builtin_bit_cast(h2v, w),
                                __builtin_bit_cast(h2v, h), acc, false);
#else
  h2v wv = __builtin_bit_cast(h2v, w);
  h2v hv = __builtin_bit_cast(h2v, h);
  return acc + (float)wv.x * (float)hv.x + (float)wv.y * (float)hv.y;
#endif
}

__device__ __forceinline__ float sigmoid_fast(float x) {
  return __fdividef(1.f, 1.f + __expf(-x));
}
__device__ __forceinline__ float tanh_fast(float x) {
  float e = __expf(2.f * fabsf(x));
  float t = 1.f - __fdividef(2.f, e + 1.f);
  return copysignf(t, x);
}

// ---------- kernel A: zero producer-consumer flags ----------
__global__ __launch_bounds__(512) void zero_flags(uint32_t* flags) {
  flags[threadIdx.x] = 0;
}

// ---------- kernel 0: f32 -> bf16 cast for W_out (8 elems/thread) ----------
__global__ __launch_bounds__(256) void cvt_bf16_kernel(
    const float* __restrict__ src, uint32_t* __restrict__ dst, int n) {
  int i = (blockIdx.x * 256 + threadIdx.x) * 8;
  if (i + 7 < n) {
    float4 a = *(const float4*)(src + i);
    float4 b = *(const float4*)(src + i + 4);
    uint4 o;
    o.x = pack_bf16(a.x, a.y);
    o.y = pack_bf16(a.z, a.w);
    o.z = pack_bf16(b.x, b.y);
    o.w = pack_bf16(b.z, b.w);
    *(uint4*)(dst + (i >> 1)) = o;
  }
}

// ---------- kernel 0c: f32 -> f16 cast (packed u32 pairs) for W_ih ----------
__global__ __launch_bounds__(256) void cvt_f16_kernel(
    const float* __restrict__ src, uint32_t* __restrict__ dst, int n) {
  int i = (blockIdx.x * 256 + threadIdx.x) * 4;
  if (i + 3 < n) {
    float4 v = *(const float4*)(src + i);
    uint2 p;
    p.x = pack_pair(v.x, v.y);
    p.y = pack_pair(v.z, v.w);
    *(uint2*)(dst + (i >> 1)) = p;
  }
}

// ---------- kernel 0b: Whh (768,256) f32 -> Wp (128,768) u32 of f16 pairs ----------
__global__ __launch_bounds__(256) void pack_whh(
    const float* __restrict__ Whh, uint32_t* __restrict__ Wp) {
  __shared__ float lds[32][257];
  int j0 = blockIdx.x * 32;
  int tid = threadIdx.x;
  #pragma unroll 4
  for (int i = 0; i < 32; ++i)
    lds[i][tid] = Whh[(size_t)(j0 + i) * 256 + tid];
  __syncthreads();
  #pragma unroll 4
  for (int i = 0; i < 16; ++i) {
    int e = i * 256 + tid;
    int k2 = e >> 5;
    int jj = e & 31;
    Wp[(size_t)k2 * 768 + j0 + jj] = pack_pair(lds[jj][2 * k2], lds[jj][2 * k2 + 1]);
  }
}

// ---------- kernel 1: embedding gather + attention -> xh (T*B, 256 u32 of f16 pairs) ----------
__global__ __launch_bounds__(256) void attn_kernel(
    const float* __restrict__ enc,    // (32,128,256)
    const int*   __restrict__ tgt,    // (32,128)
    const float* __restrict__ embt,   // (32000,256)
    uint32_t*    __restrict__ xh)     // (4096,256) u32
{
  int b   = blockIdx.x;
  int tc  = blockIdx.y;
  int tid = threadIdx.x;
  __shared__ __align__(16) float e_sh[256];
  __shared__ float attn_sh[128];
  __shared__ float red_sh[4];
  const float* encb = enc + (size_t)b * S_ * H_;

  for (int tt = 0; tt < 8; ++tt) {
    int t = tc * 8 + tt;
    int tok = (t == 0) ? 0 : tgt[b * T_ + t - 1];
    float ev = embt[(size_t)tok * E_ + tid];
    e_sh[tid] = ev;
    {
      float other = __shfl_xor(ev, 1);
      if (!(tid & 1))
        xh[(size_t)(t * B_ + b) * 256 + (tid >> 1)] = pack_pair(ev, other);
    }
    __syncthreads();

    float sc = 0.f;
    if (tid < 128) {
      const float* er = encb + tid * H_;
      #pragma unroll 8
      for (int k = 0; k < 256; k += 4) {
        float4 e4 = *(const float4*)(e_sh + k);
        float4 r4 = *(const float4*)(er + k);
        sc += e4.x * r4.x; sc += e4.y * r4.y; sc += e4.z * r4.z; sc += e4.w * r4.w;
      }
      float mx = sc;
      #pragma unroll
      for (int o = 32; o > 0; o >>= 1) mx = fmaxf(mx, __shfl_xor(mx, o, 64));
      if ((tid & 63) == 0) red_sh[tid >> 6] = mx;
    }
    __syncthreads();
    float gmax = fmaxf(red_sh[0], red_sh[1]);
    float p = 0.f;
    if (tid < 128) {
      p = __expf(sc - gmax);
      float s = p;
      #pragma unroll
      for (int o = 32; o > 0; o >>= 1) s += __shfl_xor(s, o, 64);
      if ((tid & 63) == 0) red_sh[2 + (tid >> 6)] = s;
    }
    __syncthreads();
    float tot = red_sh[2] + red_sh[3];
    if (tid < 128) attn_sh[tid] = p / tot;
    __syncthreads();

    float ctx = 0.f;
    #pragma unroll 4
    for (int s = 0; s < 128; ++s) ctx += attn_sh[s] * encb[s * H_ + tid];
    {
      float other = __shfl_xor(ctx, 1);
      if (!(tid & 1))
        xh[(size_t)(t * B_ + b) * 256 + 128 + (tid >> 1)] = pack_pair(ctx, other);
    }
    __syncthreads();
  }
}

// ---------- kernel 2: gi = xh @ W_ih^T + b_ih via f16 MFMA (M=4096,N=768,K=512) ----------
__global__ __launch_bounds__(256) void gi_gemm_f16(
    const _Float16* __restrict__ A,
    const _Float16* __restrict__ Bm,
    const float* __restrict__ bih,
    float* __restrict__ gi)
{
  __shared__ _Float16 sA[128 * 64];
  __shared__ _Float16 sB[128 * 64];
  int tid = threadIdx.x;
  int n0 = blockIdx.x * 128;
  int m0 = blockIdx.y * 128;
  int lane = tid & 63;
  int wave = tid >> 6;
  int wm = (wave >> 1) * 64;
  int wn = (wave & 1) * 64;
  int srow = tid >> 3;
  int sk   = (tid & 7) * 8;
  f32x4 acc[4][4] = {};

  for (int kt = 0; kt < 512; kt += 64) {
    #pragma unroll
    for (int it = 0; it < 4; ++it) {
      int row = it * 32 + srow;
      gll16(A  + (size_t)(m0 + row) * 512 + kt + sk, &sA[row * 64 + sk]);
      gll16(Bm + (size_t)(n0 + row) * 512 + kt + sk, &sB[row * 64 + sk]);
    }
    __syncthreads();
    #pragma unroll
    for (int kk = 0; kk < 2; ++kk) {
      f16x8 af[4], bfr[4];
      #pragma unroll
      for (int m = 0; m < 4; ++m)
        af[m] = *(const f16x8*)&sA[(wm + m * 16 + (lane & 15)) * 64 + kk * 32 + (lane >> 4) * 8];
      #pragma unroll
      for (int n = 0; n < 4; ++n)
        bfr[n] = *(const f16x8*)&sB[(wn + n * 16 + (lane & 15)) * 64 + kk * 32 + (lane >> 4) * 8];
      #pragma unroll
      for (int m = 0; m < 4; ++m)
        #pragma unroll
        for (int n = 0; n < 4; ++n)
          acc[m][n] = __builtin_amdgcn_mfma_f32_16x16x32_f16(af[m], bfr[n], acc[m][n], 0, 0, 0);
    }
    __syncthreads();
  }

  #pragma unroll
  for (int n = 0; n < 4; ++n) {
    int col = n0 + wn + n * 16 + (lane & 15);
    float bv = bih[col];
    #pragma unroll
    for (int m = 0; m < 4; ++m) {
      int rbase = m0 + wm + m * 16 + (lane >> 4) * 4;
      #pragma unroll
      for (int r = 0; r < 4; ++r)
        gi[(size_t)(rbase + r) * 768 + col] = acc[m][n][r] + bv;
    }
  }
}

// ---------- kernel 3: FUSED GRU + logits (producer-consumer, r12 protocol) ----------
// blocks 0..31: GRU (r9 structure, 170-reg budget via launch_bounds(768,3)).
// blocks 32..8031: logits m-chunk c, n-tile nn; spin flag[c]==32; swizzled
// LDS (A via VALU ds_write swizzle, B via pre-swizzled gll16 source);
// swapped MFMA; nontemporal float4 stores.
__global__ __launch_bounds__(768, 3) void gru_logits(
    const float*    __restrict__ gi,    // (4096,768)
    const uint32_t* __restrict__ Wp,    // (128,768)
    const float*    __restrict__ bhh,   // (768)
    const float*    __restrict__ h0,    // (1,32,256)
    uint32_t*       __restrict__ hsu,   // hs as (4096,128) u32 bf16-pairs
    const __hip_bfloat16* __restrict__ Bm,  // woutb (32000,256)
    const float*    __restrict__ bout,  // (32000)
    float*          __restrict__ out,   // (32,128,32000)
    uint32_t*       __restrict__ flags) // 32 x (16 u32 pad)
{
  __shared__ __align__(16) uint32_t h2[128];
  __shared__ float r_sh[256];
  __shared__ float z_sh[256];
  __shared__ __align__(16) __hip_bfloat16 sA[128 * 64];
  __shared__ __align__(16) __hip_bfloat16 sB[128 * 64];

  int bid = blockIdx.x;
  int tid = threadIdx.x;

  if (bid < 32) {
    // ================= GRU producer =================
    int b    = bid;
    int role = tid >> 8;
    int j    = tid & 255;

    uint32_t w[128];
    #pragma unroll
    for (int i = 0; i < 128; ++i) w[i] = Wp[(size_t)i * 768 + tid];
    float bj = bhh[tid];

    float hprev = 0.f;
    if (role == 2) {
      hprev = h0[b * 256 + j];
      float other = __shfl_xor(hprev, 1);
      if (!(j & 1)) h2[j >> 1] = pack_pair(hprev, other);
    }
    float gval = gi[(size_t)b * 768 + tid];
    __syncthreads();

    for (int t = 0; t < 128; ++t) {
      float gnext = 0.f;
      if (t < 127) gnext = gi[(size_t)((t + 1) * 32 + b) * 768 + tid];

      float a0 = 0.f, a1 = 0.f, a2 = 0.f, a3 = 0.f;
      float a4 = 0.f, a5 = 0.f, a6 = 0.f, a7 = 0.f;
      #pragma unroll
      for (int k8 = 0; k8 < 16; ++k8) {
        uint4 ha = *(const uint4*)&h2[k8 * 8];
        uint4 hb = *(const uint4*)&h2[k8 * 8 + 4];
        a0 = dot2(w[k8 * 8 + 0], ha.x, a0);
        a1 = dot2(w[k8 * 8 + 1], ha.y, a1);
        a2 = dot2(w[k8 * 8 + 2], ha.z, a2);
        a3 = dot2(w[k8 * 8 + 3], ha.w, a3);
        a4 = dot2(w[k8 * 8 + 4], hb.x, a4);
        a5 = dot2(w[k8 * 8 + 5], hb.y, a5);
        a6 = dot2(w[k8 * 8 + 6], hb.z, a6);
        a7 = dot2(w[k8 * 8 + 7], hb.w, a7);
      }
      float gh = ((a0 + a1) + (a2 + a3)) + ((a4 + a5) + (a6 + a7)) + bj;

      if (role == 0)      r_sh[j] = sigmoid_fast(gval + gh);
      else if (role == 1) z_sh[j] = sigmoid_fast(gval + gh);
      __syncthreads();

      if (role == 2) {
        float r = r_sh[j];
        float z = z_sh[j];
        float n = tanh_fast(gval + r * gh);
        float hn = (1.f - z) * n + z * hprev;
        hprev = hn;
        float other = __shfl_xor(hn, 1);
        if (!(j & 1)) {
          h2[j >> 1] = pack_pair(hn, other);
          __hip_atomic_store(&hsu[(size_t)(t * 32 + b) * 128 + (j >> 1)],
                             pack_bf16(hn, other),
                             __ATOMIC_RELAXED, __HIP_MEMORY_SCOPE_AGENT);
        }
      }
      gval = gnext;
      __syncthreads();   // drains hs stores before flag publish

      if ((t & 3) == 3 && tid == 0)
        __hip_atomic_fetch_add(&flags[(t >> 2) * 16], 1u,
                               __ATOMIC_RELEASE, __HIP_MEMORY_SCOPE_AGENT);
    }
    return;
  }

  // ================= logits consumer =================
  if (tid >= 256) return;   // waves 4-11 exit
  int bid2 = bid - 32;
  int c  = bid2 / 250;      // m-chunk, produced in ascending order
  int nn = bid2 % 250;
  int m0 = c * 128;
  int n0 = nn * 128;
  int lane = tid & 63;
  int wave = tid >> 6;
  int wm = (wave >> 1) * 64;
  int wn = (wave & 1) * 64;
  int srow = tid >> 3;
  int schunk = tid & 7;

  if (tid == 0) {
    while (__hip_atomic_load(&flags[c * 16], __ATOMIC_ACQUIRE,
                             __HIP_MEMORY_SCOPE_AGENT) < 32u)
      __builtin_amdgcn_s_sleep(32);
  }
  __syncthreads();

  uint32_t* sAu = (uint32_t*)sA;
  f32x4 acc[4][4] = {};

  for (int kt = 0; kt < 256; kt += 64) {
    // A stage: device-scope loads -> swizzled LDS (VALU path controls dest)
    #pragma unroll
    for (int i = 0; i < 16; ++i) {
      int e = i * 256 + tid;          // 0..4095
      int row = e >> 5;
      int cu  = e & 31;               // u32 col within 32-u32 row
      uint32_t v = __hip_atomic_load(&hsu[(size_t)(m0 + row) * 128 + (kt >> 1) + cu],
                                     __ATOMIC_RELAXED, __HIP_MEMORY_SCOPE_AGENT);
      int sc16 = (cu >> 2) ^ (row & 7);            // swizzled 16B chunk
      sAu[row * 32 + sc16 * 4 + (cu & 3)] = v;
    }
    // B stage: gll16 with pre-swizzled global source (r13/r17-verified)
    #pragma unroll
    for (int it = 0; it < 4; ++it) {
      int row = it * 32 + srow;
      int gc = ((schunk ^ (row & 7)) * 8);
      gll16(Bm + (size_t)(n0 + row) * 256 + kt + gc, &sB[row * 64 + schunk * 8]);
    }
    __syncthreads();
    #pragma unroll
    for (int kk = 0; kk < 2; ++kk) {
      bf16x8 af[4], bfr[4];
      #pragma unroll
      for (int m = 0; m < 4; ++m) {
        int r = wm + m * 16 + (lane & 15);
        int pc = ((kk * 4 + (lane >> 4)) ^ (r & 7)) * 8;
        af[m] = *(const bf16x8*)&sA[r * 64 + pc];
      }
      #pragma unroll
      for (int n = 0; n < 4; ++n) {
        int r = wn + n * 16 + (lane & 15);
        int pc = ((kk * 4 + (lane >> 4)) ^ (r & 7)) * 8;
        bfr[n] = *(const bf16x8*)&sB[r * 64 + pc];
      }
      #pragma unroll
      for (int m = 0; m < 4; ++m)
        #pragma unroll
        for (int n = 0; n < 4; ++n)
          acc[m][n] = __builtin_amdgcn_mfma_f32_16x16x32_bf16(bfr[n], af[m], acc[m][n], 0, 0, 0);
    }
    __syncthreads();
  }

  #pragma unroll
  for (int m = 0; m < 4; ++m) {
    int row = m0 + wm + m * 16 + (lane & 15);
    int t  = row >> 5;
    int bb = row & 31;
    float* orow = out + (size_t)(bb * 128 + t) * 32000;
    #pragma unroll
    for (int n = 0; n < 4; ++n) {
      int col0 = n0 + wn + n * 16 + (lane >> 4) * 4;
      f32x4 bv = *(const f32x4*)&bout[col0];
      f32x4 v = acc[m][n] + bv;
      __builtin_nontemporal_store(v, (f32x4*)&orow[col0]);
    }
  }
}

extern "C" void kernel_launch(void* const* d_in, const int* in_sizes, int n_in,
                              void* d_out, int out_size, void* d_ws, size_t ws_size,
                              hipStream_t stream) {
  const float* enc  = (const float*)d_in[0];
  const float* ench = (const float*)d_in[1];
  const int*   tgt  = (const int*)d_in[2];
  const float* embt = (const float*)d_in[3];
  const float* Wih  = (const float*)d_in[4];
  const float* Whh  = (const float*)d_in[5];
  const float* bih  = (const float*)d_in[6];
  const float* bhh  = (const float*)d_in[7];
  const float* Wout = (const float*)d_in[8];
  const float* bout = (const float*)d_in[9];
  float* out = (float*)d_out;

  char* ws = (char*)d_ws;
  float*          gi    = (float*)(ws);                          // 12,582,912 B
  uint32_t*       hsu   = (uint32_t*)(ws + 12582912);            //  2,097,152 B
  __hip_bfloat16* woutb = (__hip_bfloat16*)(ws + 14680064);      // 16,384,000 B
  uint32_t*       xh    = (uint32_t*)(ws + 31064064);            //  4,194,304 B
  uint32_t*       wihh  = (uint32_t*)(ws + 35258368);            //    786,432 B
  uint32_t*       flags = (uint32_t*)(ws + 36044800);            //      2,048 B

  // Wp in the TAIL of d_out: dead before chunk-31 logits blocks run
  // (they wait for all GRU blocks, which load Wp only at start).
  uint32_t* Wp = (uint32_t*)(out + ((size_t)out_size - 98304));

  zero_flags<<<1, 512, 0, stream>>>(flags);
  cvt_bf16_kernel<<<4000, 256, 0, stream>>>(Wout, (uint32_t*)woutb, V_ * H_);
  cvt_f16_kernel<<<384, 256, 0, stream>>>(Wih, wihh, 768 * 512);
  pack_whh<<<24, 256, 0, stream>>>(Whh, Wp);
  attn_kernel<<<dim3(32, 16), 256, 0, stream>>>(enc, tgt, embt, xh);
  gi_gemm_f16<<<dim3(6, 32), 256, 0, stream>>>((const _Float16*)xh, (const _Float16*)wihh, bih, gi);
  gru_logits<<<8032, 768, 0, stream>>>(gi, Wp, bhh, ench, hsu, woutb, bout, out, flags);
}

// Round 19
// 718.775 us; speedup vs baseline: 1.0154x; 1.0154x over previous
//
#include <hip/hip_runtime.h>
#include <hip/hip_bf16.h>
#include <stdint.h>

typedef float    f32x4  __attribute__((ext_vector_type(4)));
typedef __bf16   bf16x8 __attribute__((ext_vector_type(8)));
typedef _Float16 f16x8  __attribute__((ext_vector_type(8)));
typedef _Float16 h2v    __attribute__((ext_vector_type(2)));

#define B_ 32
#define S_ 128
#define T_ 128
#define H_ 256
#define E_ 256
#define V_ 32000

// ---------- async global->LDS (16B per lane) ----------
__device__ __forceinline__ void gll16(const void* g, void* l) {
  __builtin_amdgcn_global_load_lds(
      (const __attribute__((address_space(1))) uint32_t*)g,
      (__attribute__((address_space(3))) uint32_t*)l,
      16, 0, 0);
}

__device__ __forceinline__ uint32_t pack_pair(float a, float b) {
  unsigned short lo = __builtin_bit_cast(unsigned short, (_Float16)a);
  unsigned short hi = __builtin_bit_cast(unsigned short, (_Float16)b);
  return (uint32_t)lo | ((uint32_t)hi << 16);
}

__device__ __forceinline__ uint32_t pack_bf16(float a, float b) {
  return (uint32_t)__builtin_bit_cast(unsigned short, __float2bfloat16(a)) |
         ((uint32_t)__builtin_bit_cast(unsigned short, __float2bfloat16(b)) << 16);
}

__device__ __forceinline__ float dot2(uint32_t w, uint32_t h, float acc) {
#if __has_builtin(__builtin_amdgcn_fdot2)
  return __builtin_amdgcn_fdot2(__builtin_bit_cast(h2v, w),
                                __builtin_bit_cast(h2v, h), acc, false);
#else
  h2v wv = __builtin_bit_cast(h2v, w);
  h2v hv = __builtin_bit_cast(h2v, h);
  return acc + (float)wv.x * (float)hv.x + (float)wv.y * (float)hv.y;
#endif
}

__device__ __forceinline__ float sigmoid_fast(float x) {
  return __fdividef(1.f, 1.f + __expf(-x));
}
__device__ __forceinline__ float tanh_fast(float x) {
  float e = __expf(2.f * fabsf(x));
  float t = 1.f - __fdividef(2.f, e + 1.f);
  return copysignf(t, x);
}

// ---------- kernel A: zero producer-consumer flags ----------
__global__ __launch_bounds__(512) void zero_flags(uint32_t* flags) {
  flags[threadIdx.x] = 0;
}

// ---------- kernel 0: f32 -> bf16 cast for W_out (8 elems/thread) ----------
__global__ __launch_bounds__(256) void cvt_bf16_kernel(
    const float* __restrict__ src, uint32_t* __restrict__ dst, int n) {
  int i = (blockIdx.x * 256 + threadIdx.x) * 8;
  if (i + 7 < n) {
    float4 a = *(const float4*)(src + i);
    float4 b = *(const float4*)(src + i + 4);
    uint4 o;
    o.x = pack_bf16(a.x, a.y);
    o.y = pack_bf16(a.z, a.w);
    o.z = pack_bf16(b.x, b.y);
    o.w = pack_bf16(b.z, b.w);
    *(uint4*)(dst + (i >> 1)) = o;
  }
}

// ---------- kernel 0c: f32 -> f16 cast (packed u32 pairs) for W_ih ----------
__global__ __launch_bounds__(256) void cvt_f16_kernel(
    const float* __restrict__ src, uint32_t* __restrict__ dst, int n) {
  int i = (blockIdx.x * 256 + threadIdx.x) * 4;
  if (i + 3 < n) {
    float4 v = *(const float4*)(src + i);
    uint2 p;
    p.x = pack_pair(v.x, v.y);
    p.y = pack_pair(v.z, v.w);
    *(uint2*)(dst + (i >> 1)) = p;
  }
}

// ---------- kernel 0b: Whh (768,256) f32 -> Wp (128,768) u32 of f16 pairs ----------
__global__ __launch_bounds__(256) void pack_whh(
    const float* __restrict__ Whh, uint32_t* __restrict__ Wp) {
  __shared__ float lds[32][257];
  int j0 = blockIdx.x * 32;
  int tid = threadIdx.x;
  #pragma unroll 4
  for (int i = 0; i < 32; ++i)
    lds[i][tid] = Whh[(size_t)(j0 + i) * 256 + tid];
  __syncthreads();
  #pragma unroll 4
  for (int i = 0; i < 16; ++i) {
    int e = i * 256 + tid;
    int k2 = e >> 5;
    int jj = e & 31;
    Wp[(size_t)k2 * 768 + j0 + jj] = pack_pair(lds[jj][2 * k2], lds[jj][2 * k2 + 1]);
  }
}

// ---------- kernel 1: embedding gather + attention -> xh (T*B, 256 u32 of f16 pairs) ----------
__global__ __launch_bounds__(256) void attn_kernel(
    const float* __restrict__ enc,    // (32,128,256)
    const int*   __restrict__ tgt,    // (32,128)
    const float* __restrict__ embt,   // (32000,256)
    uint32_t*    __restrict__ xh)     // (4096,256) u32
{
  int b   = blockIdx.x;
  int tc  = blockIdx.y;
  int tid = threadIdx.x;
  __shared__ __align__(16) float e_sh[256];
  __shared__ float attn_sh[128];
  __shared__ float red_sh[4];
  const float* encb = enc + (size_t)b * S_ * H_;

  for (int tt = 0; tt < 8; ++tt) {
    int t = tc * 8 + tt;
    int tok = (t == 0) ? 0 : tgt[b * T_ + t - 1];
    float ev = embt[(size_t)tok * E_ + tid];
    e_sh[tid] = ev;
    {
      float other = __shfl_xor(ev, 1);
      if (!(tid & 1))
        xh[(size_t)(t * B_ + b) * 256 + (tid >> 1)] = pack_pair(ev, other);
    }
    __syncthreads();

    float sc = 0.f;
    if (tid < 128) {
      const float* er = encb + tid * H_;
      #pragma unroll 8
      for (int k = 0; k < 256; k += 4) {
        float4 e4 = *(const float4*)(e_sh + k);
        float4 r4 = *(const float4*)(er + k);
        sc += e4.x * r4.x; sc += e4.y * r4.y; sc += e4.z * r4.z; sc += e4.w * r4.w;
      }
      float mx = sc;
      #pragma unroll
      for (int o = 32; o > 0; o >>= 1) mx = fmaxf(mx, __shfl_xor(mx, o, 64));
      if ((tid & 63) == 0) red_sh[tid >> 6] = mx;
    }
    __syncthreads();
    float gmax = fmaxf(red_sh[0], red_sh[1]);
    float p = 0.f;
    if (tid < 128) {
      p = __expf(sc - gmax);
      float s = p;
      #pragma unroll
      for (int o = 32; o > 0; o >>= 1) s += __shfl_xor(s, o, 64);
      if ((tid & 63) == 0) red_sh[2 + (tid >> 6)] = s;
    }
    __syncthreads();
    float tot = red_sh[2] + red_sh[3];
    if (tid < 128) attn_sh[tid] = p / tot;
    __syncthreads();

    float ctx = 0.f;
    #pragma unroll 4
    for (int s = 0; s < 128; ++s) ctx += attn_sh[s] * encb[s * H_ + tid];
    {
      float other = __shfl_xor(ctx, 1);
      if (!(tid & 1))
        xh[(size_t)(t * B_ + b) * 256 + 128 + (tid >> 1)] = pack_pair(ctx, other);
    }
    __syncthreads();
  }
}

// ---------- kernel 2: gi = xh @ W_ih^T + b_ih via f16 MFMA (M=4096,N=768,K=512) ----------
__global__ __launch_bounds__(256) void gi_gemm_f16(
    const _Float16* __restrict__ A,
    const _Float16* __restrict__ Bm,
    const float* __restrict__ bih,
    float* __restrict__ gi)
{
  __shared__ _Float16 sA[128 * 64];
  __shared__ _Float16 sB[128 * 64];
  int tid = threadIdx.x;
  int n0 = blockIdx.x * 128;
  int m0 = blockIdx.y * 128;
  int lane = tid & 63;
  int wave = tid >> 6;
  int wm = (wave >> 1) * 64;
  int wn = (wave & 1) * 64;
  int srow = tid >> 3;
  int sk   = (tid & 7) * 8;
  f32x4 acc[4][4] = {};

  for (int kt = 0; kt < 512; kt += 64) {
    #pragma unroll
    for (int it = 0; it < 4; ++it) {
      int row = it * 32 + srow;
      gll16(A  + (size_t)(m0 + row) * 512 + kt + sk, &sA[row * 64 + sk]);
      gll16(Bm + (size_t)(n0 + row) * 512 + kt + sk, &sB[row * 64 + sk]);
    }
    __syncthreads();
    #pragma unroll
    for (int kk = 0; kk < 2; ++kk) {
      f16x8 af[4], bfr[4];
      #pragma unroll
      for (int m = 0; m < 4; ++m)
        af[m] = *(const f16x8*)&sA[(wm + m * 16 + (lane & 15)) * 64 + kk * 32 + (lane >> 4) * 8];
      #pragma unroll
      for (int n = 0; n < 4; ++n)
        bfr[n] = *(const f16x8*)&sB[(wn + n * 16 + (lane & 15)) * 64 + kk * 32 + (lane >> 4) * 8];
      #pragma unroll
      for (int m = 0; m < 4; ++m)
        #pragma unroll
        for (int n = 0; n < 4; ++n)
          acc[m][n] = __builtin_amdgcn_mfma_f32_16x16x32_f16(af[m], bfr[n], acc[m][n], 0, 0, 0);
    }
    __syncthreads();
  }

  #pragma unroll
  for (int n = 0; n < 4; ++n) {
    int col = n0 + wn + n * 16 + (lane & 15);
    float bv = bih[col];
    #pragma unroll
    for (int m = 0; m < 4; ++m) {
      int rbase = m0 + wm + m * 16 + (lane >> 4) * 4;
      #pragma unroll
      for (int r = 0; r < 4; ++r)
        gi[(size_t)(rbase + r) * 768 + col] = acc[m][n][r] + bv;
    }
  }
}

// ---------- kernel 3: FUSED GRU + logits (producer-consumer) ----------
// amdgpu_waves_per_eu(3,3): PIN occupancy to 3 waves/EU (1x768-thread block/CU)
// so the register budget is ~170 and the GRU branch's w[128] stays in VGPRs.
// (r18's launch_bounds(768,3) set only the MIN; backend targeted 6/EU -> 84
// regs -> spill. This caps the MAX too.)
__global__ __launch_bounds__(768)
__attribute__((amdgpu_waves_per_eu(3, 3)))
void gru_logits(
    const float*    __restrict__ gi,    // (4096,768)
    const uint32_t* __restrict__ Wp,    // (128,768)
    const float*    __restrict__ bhh,   // (768)
    const float*    __restrict__ h0,    // (1,32,256)
    uint32_t*       __restrict__ hsu,   // hs as (4096,128) u32 bf16-pairs
    const __hip_bfloat16* __restrict__ Bm,  // woutb (32000,256)
    const float*    __restrict__ bout,  // (32000)
    float*          __restrict__ out,   // (32,128,32000)
    uint32_t*       __restrict__ flags) // 32 x (16 u32 pad)
{
  __shared__ __align__(16) uint32_t h2[128];
  __shared__ float r_sh[256];
  __shared__ float z_sh[256];
  __shared__ __align__(16) __hip_bfloat16 sA[128 * 64];
  __shared__ __align__(16) __hip_bfloat16 sB[128 * 64];

  int bid = blockIdx.x;
  int tid = threadIdx.x;

  if (bid < 32) {
    // ================= GRU producer =================
    int b    = bid;
    int role = tid >> 8;
    int j    = tid & 255;

    uint32_t w[128];
    #pragma unroll
    for (int i = 0; i < 128; ++i) w[i] = Wp[(size_t)i * 768 + tid];
    float bj = bhh[tid];

    float hprev = 0.f;
    if (role == 2) {
      hprev = h0[b * 256 + j];
      float other = __shfl_xor(hprev, 1);
      if (!(j & 1)) h2[j >> 1] = pack_pair(hprev, other);
    }
    float gval = gi[(size_t)b * 768 + tid];
    __syncthreads();

    for (int t = 0; t < 128; ++t) {
      float gnext = 0.f;
      if (t < 127) gnext = gi[(size_t)((t + 1) * 32 + b) * 768 + tid];

      float a0 = 0.f, a1 = 0.f, a2 = 0.f, a3 = 0.f;
      float a4 = 0.f, a5 = 0.f, a6 = 0.f, a7 = 0.f;
      #pragma unroll
      for (int k8 = 0; k8 < 16; ++k8) {
        uint4 ha = *(const uint4*)&h2[k8 * 8];
        uint4 hb = *(const uint4*)&h2[k8 * 8 + 4];
        a0 = dot2(w[k8 * 8 + 0], ha.x, a0);
        a1 = dot2(w[k8 * 8 + 1], ha.y, a1);
        a2 = dot2(w[k8 * 8 + 2], ha.z, a2);
        a3 = dot2(w[k8 * 8 + 3], ha.w, a3);
        a4 = dot2(w[k8 * 8 + 4], hb.x, a4);
        a5 = dot2(w[k8 * 8 + 5], hb.y, a5);
        a6 = dot2(w[k8 * 8 + 6], hb.z, a6);
        a7 = dot2(w[k8 * 8 + 7], hb.w, a7);
      }
      float gh = ((a0 + a1) + (a2 + a3)) + ((a4 + a5) + (a6 + a7)) + bj;

      if (role == 0)      r_sh[j] = sigmoid_fast(gval + gh);
      else if (role == 1) z_sh[j] = sigmoid_fast(gval + gh);
      __syncthreads();

      if (role == 2) {
        float r = r_sh[j];
        float z = z_sh[j];
        float n = tanh_fast(gval + r * gh);
        float hn = (1.f - z) * n + z * hprev;
        hprev = hn;
        float other = __shfl_xor(hn, 1);
        if (!(j & 1)) {
          h2[j >> 1] = pack_pair(hn, other);
          __hip_atomic_store(&hsu[(size_t)(t * 32 + b) * 128 + (j >> 1)],
                             pack_bf16(hn, other),
                             __ATOMIC_RELAXED, __HIP_MEMORY_SCOPE_AGENT);
        }
      }
      gval = gnext;
      __syncthreads();   // drains hs stores before flag publish

      if ((t & 3) == 3 && tid == 0)
        __hip_atomic_fetch_add(&flags[(t >> 2) * 16], 1u,
                               __ATOMIC_RELEASE, __HIP_MEMORY_SCOPE_AGENT);
    }
    return;
  }

  // ================= logits consumer =================
  if (tid >= 256) return;   // waves 4-11 exit, freeing their registers
  int bid2 = bid - 32;
  int c  = bid2 / 250;      // m-chunk, produced in ascending order
  int nn = bid2 % 250;
  int m0 = c * 128;
  int n0 = nn * 128;
  int lane = tid & 63;
  int wave = tid >> 6;
  int wm = (wave >> 1) * 64;
  int wn = (wave & 1) * 64;
  int srow = tid >> 3;
  int schunk = tid & 7;

  if (tid == 0) {
    while (__hip_atomic_load(&flags[c * 16], __ATOMIC_ACQUIRE,
                             __HIP_MEMORY_SCOPE_AGENT) < 32u)
      __builtin_amdgcn_s_sleep(32);
  }
  __syncthreads();

  uint32_t* sAu = (uint32_t*)sA;
  f32x4 acc[4][4] = {};

  for (int kt = 0; kt < 256; kt += 64) {
    // A stage: device-scope loads -> swizzled LDS (VALU path controls dest)
    #pragma unroll
    for (int i = 0; i < 16; ++i) {
      int e = i * 256 + tid;          // 0..4095
      int row = e >> 5;
      int cu  = e & 31;               // u32 col within 32-u32 row
      uint32_t v = __hip_atomic_load(&hsu[(size_t)(m0 + row) * 128 + (kt >> 1) + cu],
                                     __ATOMIC_RELAXED, __HIP_MEMORY_SCOPE_AGENT);
      int sc16 = (cu >> 2) ^ (row & 7);            // swizzled 16B chunk
      sAu[row * 32 + sc16 * 4 + (cu & 3)] = v;
    }
    // B stage: gll16 with pre-swizzled global source (r13/r17-verified)
    #pragma unroll
    for (int it = 0; it < 4; ++it) {
      int row = it * 32 + srow;
      int gc = ((schunk ^ (row & 7)) * 8);
      gll16(Bm + (size_t)(n0 + row) * 256 + kt + gc, &sB[row * 64 + schunk * 8]);
    }
    __syncthreads();
    #pragma unroll
    for (int kk = 0; kk < 2; ++kk) {
      bf16x8 af[4], bfr[4];
      #pragma unroll
      for (int m = 0; m < 4; ++m) {
        int r = wm + m * 16 + (lane & 15);
        int pc = ((kk * 4 + (lane >> 4)) ^ (r & 7)) * 8;
        af[m] = *(const bf16x8*)&sA[r * 64 + pc];
      }
      #pragma unroll
      for (int n = 0; n < 4; ++n) {
        int r = wn + n * 16 + (lane & 15);
        int pc = ((kk * 4 + (lane >> 4)) ^ (r & 7)) * 8;
        bfr[n] = *(const bf16x8*)&sB[r * 64 + pc];
      }
      #pragma unroll
      for (int m = 0; m < 4; ++m)
        #pragma unroll
        for (int n = 0; n < 4; ++n)
          acc[m][n] = __builtin_amdgcn_mfma_f32_16x16x32_bf16(bfr[n], af[m], acc[m][n], 0, 0, 0);
    }
    __syncthreads();
  }

  #pragma unroll
  for (int m = 0; m < 4; ++m) {
    int row = m0 + wm + m * 16 + (lane & 15);
    int t  = row >> 5;
    int bb = row & 31;
    float* orow = out + (size_t)(bb * 128 + t) * 32000;
    #pragma unroll
    for (int n = 0; n < 4; ++n) {
      int col0 = n0 + wn + n * 16 + (lane >> 4) * 4;
      f32x4 bv = *(const f32x4*)&bout[col0];
      f32x4 v = acc[m][n] + bv;
      __builtin_nontemporal_store(v, (f32x4*)&orow[col0]);
    }
  }
}

extern "C" void kernel_launch(void* const* d_in, const int* in_sizes, int n_in,
                              void* d_out, int out_size, void* d_ws, size_t ws_size,
                              hipStream_t stream) {
  const float* enc  = (const float*)d_in[0];
  const float* ench = (const float*)d_in[1];
  const int*   tgt  = (const int*)d_in[2];
  const float* embt = (const float*)d_in[3];
  const float* Wih  = (const float*)d_in[4];
  const float* Whh  = (const float*)d_in[5];
  const float* bih  = (const float*)d_in[6];
  const float* bhh  = (const float*)d_in[7];
  const float* Wout = (const float*)d_in[8];
  const float* bout = (const float*)d_in[9];
  float* out = (float*)d_out;

  char* ws = (char*)d_ws;
  float*          gi    = (float*)(ws);                          // 12,582,912 B
  uint32_t*       hsu   = (uint32_t*)(ws + 12582912);            //  2,097,152 B
  __hip_bfloat16* woutb = (__hip_bfloat16*)(ws + 14680064);      // 16,384,000 B
  uint32_t*       xh    = (uint32_t*)(ws + 31064064);            //  4,194,304 B
  uint32_t*       wihh  = (uint32_t*)(ws + 35258368);            //    786,432 B
  uint32_t*       flags = (uint32_t*)(ws + 36044800);            //      2,048 B

  // Wp in the TAIL of d_out: dead before chunk-31 logits blocks run.
  uint32_t* Wp = (uint32_t*)(out + ((size_t)out_size - 98304));

  zero_flags<<<1, 512, 0, stream>>>(flags);
  cvt_bf16_kernel<<<4000, 256, 0, stream>>>(Wout, (uint32_t*)woutb, V_ * H_);
  cvt_f16_kernel<<<384, 256, 0, stream>>>(Wih, wihh, 768 * 512);
  pack_whh<<<24, 256, 0, stream>>>(Whh, Wp);
  attn_kernel<<<dim3(32, 16), 256, 0, stream>>>(enc, tgt, embt, xh);
  gi_gemm_f16<<<dim3(6, 32), 256, 0, stream>>>((const _Float16*)xh, (const _Float16*)wihh, bih, gi);
  gru_logits<<<8032, 768, 0, stream>>>(gi, Wp, bhh, ench, hsu, woutb, bout, out, flags);
}

// Round 20
// 470.786 us; speedup vs baseline: 1.5503x; 1.5268x over previous
//
#include <hip/hip_runtime.h>
#include <hip/hip_bf16.h>
#include <stdint.h>

typedef float    f32x4  __attribute__((ext_vector_type(4)));
typedef __bf16   bf16x8 __attribute__((ext_vector_type(8)));
typedef _Float16 f16x8  __attribute__((ext_vector_type(8)));
typedef _Float16 h2v    __attribute__((ext_vector_type(2)));

#define B_ 32
#define S_ 128
#define T_ 128
#define H_ 256
#define E_ 256
#define V_ 32000

// ---------- async global->LDS (16B per lane) ----------
__device__ __forceinline__ void gll16(const void* g, void* l) {
  __builtin_amdgcn_global_load_lds(
      (const __attribute__((address_space(1))) uint32_t*)g,
      (__attribute__((address_space(3))) uint32_t*)l,
      16, 0, 0);
}

__device__ __forceinline__ uint32_t pack_pair(float a, float b) {
  unsigned short lo = __builtin_bit_cast(unsigned short, (_Float16)a);
  unsigned short hi = __builtin_bit_cast(unsigned short, (_Float16)b);
  return (uint32_t)lo | ((uint32_t)hi << 16);
}

__device__ __forceinline__ uint32_t pack_bf16(float a, float b) {
  return (uint32_t)__builtin_bit_cast(unsigned short, __float2bfloat16(a)) |
         ((uint32_t)__builtin_bit_cast(unsigned short, __float2bfloat16(b)) << 16);
}

__device__ __forceinline__ float dot2(uint32_t w, uint32_t h, float acc) {
#if __has_builtin(__builtin_amdgcn_fdot2)
  return __builtin_amdgcn_fdot2(__builtin_bit_cast(h2v, w),
                                __builtin_bit_cast(h2v, h), acc, false);
#else
  h2v wv = __builtin_bit_cast(h2v, w);
  h2v hv = __builtin_bit_cast(h2v, h);
  return acc + (float)wv.x * (float)hv.x + (float)wv.y * (float)hv.y;
#endif
}

__device__ __forceinline__ float sigmoid_fast(float x) {
  return __fdividef(1.f, 1.f + __expf(-x));
}
__device__ __forceinline__ float tanh_fast(float x) {
  float e = __expf(2.f * fabsf(x));
  float t = 1.f - __fdividef(2.f, e + 1.f);
  return copysignf(t, x);
}

// ---------- kernel 0: f32 -> bf16 cast for W_out (8 elems/thread) ----------
__global__ __launch_bounds__(256) void cvt_bf16_kernel(
    const float* __restrict__ src, uint32_t* __restrict__ dst, int n) {
  int i = (blockIdx.x * 256 + threadIdx.x) * 8;
  if (i + 7 < n) {
    float4 a = *(const float4*)(src + i);
    float4 b = *(const float4*)(src + i + 4);
    uint4 o;
    o.x = pack_bf16(a.x, a.y);
    o.y = pack_bf16(a.z, a.w);
    o.z = pack_bf16(b.x, b.y);
    o.w = pack_bf16(b.z, b.w);
    *(uint4*)(dst + (i >> 1)) = o;
  }
}

// ---------- kernel 0c: f32 -> f16 cast (packed u32 pairs) for W_ih ----------
__global__ __launch_bounds__(256) void cvt_f16_kernel(
    const float* __restrict__ src, uint32_t* __restrict__ dst, int n) {
  int i = (blockIdx.x * 256 + threadIdx.x) * 4;
  if (i + 3 < n) {
    float4 v = *(const float4*)(src + i);
    uint2 p;
    p.x = pack_pair(v.x, v.y);
    p.y = pack_pair(v.z, v.w);
    *(uint2*)(dst + (i >> 1)) = p;
  }
}

// ---------- kernel 0b: Whh (768,256) f32 -> Wp (128,768) u32 of f16 pairs ----------
__global__ __launch_bounds__(256) void pack_whh(
    const float* __restrict__ Whh, uint32_t* __restrict__ Wp) {
  __shared__ float lds[32][257];
  int j0 = blockIdx.x * 32;
  int tid = threadIdx.x;
  #pragma unroll 4
  for (int i = 0; i < 32; ++i)
    lds[i][tid] = Whh[(size_t)(j0 + i) * 256 + tid];
  __syncthreads();
  #pragma unroll 4
  for (int i = 0; i < 16; ++i) {
    int e = i * 256 + tid;
    int k2 = e >> 5;
    int jj = e & 31;
    Wp[(size_t)k2 * 768 + j0 + jj] = pack_pair(lds[jj][2 * k2], lds[jj][2 * k2 + 1]);
  }
}

// ---------- kernel 1: embedding gather + attention -> xh (T*B, 256 u32 of f16 pairs) ----------
__global__ __launch_bounds__(256) void attn_kernel(
    const float* __restrict__ enc,    // (32,128,256)
    const int*   __restrict__ tgt,    // (32,128)
    const float* __restrict__ embt,   // (32000,256)
    uint32_t*    __restrict__ xh)     // (4096,256) u32: [emb f16x512 | ctx]
{
  int b   = blockIdx.x;
  int tc  = blockIdx.y;
  int tid = threadIdx.x;
  __shared__ __align__(16) float e_sh[256];
  __shared__ float attn_sh[128];
  __shared__ float red_sh[4];
  const float* encb = enc + (size_t)b * S_ * H_;

  for (int tt = 0; tt < 8; ++tt) {
    int t = tc * 8 + tt;
    int tok = (t == 0) ? 0 : tgt[b * T_ + t - 1];
    float ev = embt[(size_t)tok * E_ + tid];
    e_sh[tid] = ev;
    {
      float other = __shfl_xor(ev, 1);
      if (!(tid & 1))
        xh[(size_t)(t * B_ + b) * 256 + (tid >> 1)] = pack_pair(ev, other);
    }
    __syncthreads();

    float sc = 0.f;
    if (tid < 128) {
      const float* er = encb + tid * H_;
      #pragma unroll 8
      for (int k = 0; k < 256; k += 4) {
        float4 e4 = *(const float4*)(e_sh + k);
        float4 r4 = *(const float4*)(er + k);
        sc += e4.x * r4.x; sc += e4.y * r4.y; sc += e4.z * r4.z; sc += e4.w * r4.w;
      }
      float mx = sc;
      #pragma unroll
      for (int o = 32; o > 0; o >>= 1) mx = fmaxf(mx, __shfl_xor(mx, o, 64));
      if ((tid & 63) == 0) red_sh[tid >> 6] = mx;
    }
    __syncthreads();
    float gmax = fmaxf(red_sh[0], red_sh[1]);
    float p = 0.f;
    if (tid < 128) {
      p = __expf(sc - gmax);
      float s = p;
      #pragma unroll
      for (int o = 32; o > 0; o >>= 1) s += __shfl_xor(s, o, 64);
      if ((tid & 63) == 0) red_sh[2 + (tid >> 6)] = s;
    }
    __syncthreads();
    float tot = red_sh[2] + red_sh[3];
    if (tid < 128) attn_sh[tid] = p / tot;
    __syncthreads();

    float ctx = 0.f;
    #pragma unroll 4
    for (int s = 0; s < 128; ++s) ctx += attn_sh[s] * encb[s * H_ + tid];
    {
      float other = __shfl_xor(ctx, 1);
      if (!(tid & 1))
        xh[(size_t)(t * B_ + b) * 256 + 128 + (tid >> 1)] = pack_pair(ctx, other);
    }
    __syncthreads();
  }
}

// ---------- kernel 2: gi = xh @ W_ih^T + b_ih via f16 MFMA (M=4096,N=768,K=512) ----------
__global__ __launch_bounds__(256) void gi_gemm_f16(
    const _Float16* __restrict__ A,
    const _Float16* __restrict__ Bm,
    const float* __restrict__ bih,
    float* __restrict__ gi)
{
  __shared__ _Float16 sA[128 * 64];
  __shared__ _Float16 sB[128 * 64];
  int tid = threadIdx.x;
  int n0 = blockIdx.x * 128;
  int m0 = blockIdx.y * 128;
  int lane = tid & 63;
  int wave = tid >> 6;
  int wm = (wave >> 1) * 64;
  int wn = (wave & 1) * 64;
  int srow = tid >> 3;
  int sk   = (tid & 7) * 8;
  f32x4 acc[4][4] = {};

  for (int kt = 0; kt < 512; kt += 64) {
    #pragma unroll
    for (int it = 0; it < 4; ++it) {
      int row = it * 32 + srow;
      gll16(A  + (size_t)(m0 + row) * 512 + kt + sk, &sA[row * 64 + sk]);
      gll16(Bm + (size_t)(n0 + row) * 512 + kt + sk, &sB[row * 64 + sk]);
    }
    __syncthreads();
    #pragma unroll
    for (int kk = 0; kk < 2; ++kk) {
      f16x8 af[4], bfr[4];
      #pragma unroll
      for (int m = 0; m < 4; ++m)
        af[m] = *(const f16x8*)&sA[(wm + m * 16 + (lane & 15)) * 64 + kk * 32 + (lane >> 4) * 8];
      #pragma unroll
      for (int n = 0; n < 4; ++n)
        bfr[n] = *(const f16x8*)&sB[(wn + n * 16 + (lane & 15)) * 64 + kk * 32 + (lane >> 4) * 8];
      #pragma unroll
      for (int m = 0; m < 4; ++m)
        #pragma unroll
        for (int n = 0; n < 4; ++n)
          acc[m][n] = __builtin_amdgcn_mfma_f32_16x16x32_f16(af[m], bfr[n], acc[m][n], 0, 0, 0);
    }
    __syncthreads();
  }

  #pragma unroll
  for (int n = 0; n < 4; ++n) {
    int col = n0 + wn + n * 16 + (lane & 15);
    float bv = bih[col];
    #pragma unroll
    for (int m = 0; m < 4; ++m) {
      int rbase = m0 + wm + m * 16 + (lane >> 4) * 4;
      #pragma unroll
      for (int r = 0; r < 4; ++r)
        gi[(size_t)(rbase + r) * 768 + col] = acc[m][n][r] + bv;
    }
  }
}

// ---------- kernel 3: GRU recurrence (r9 known-good) ----------
__global__ __launch_bounds__(768) void gru_kernel(
    const float*    __restrict__ gi,   // (4096,768)  rows = t*32+b
    const uint32_t* __restrict__ Wp,   // (128,768) u32 = f16 pair
    const float*    __restrict__ bhh,  // (768)
    const float*    __restrict__ h0,   // (1,32,256)
    __hip_bfloat16* __restrict__ hs)   // (4096,256) bf16
{
  int b   = blockIdx.x;
  int tid = threadIdx.x;  // 0..767
  int role = tid >> 8;    // 0=r, 1=z, 2=n
  int j    = tid & 255;
  __shared__ __align__(16) uint32_t h2[128];
  __shared__ float r_sh[256];
  __shared__ float z_sh[256];

  uint32_t w[128];
  #pragma unroll
  for (int i = 0; i < 128; ++i) w[i] = Wp[(size_t)i * 768 + tid];
  float bj = bhh[tid];

  float hprev = 0.f;
  if (role == 2) {
    hprev = h0[b * 256 + j];
    float other = __shfl_xor(hprev, 1);
    if (!(j & 1)) h2[j >> 1] = pack_pair(hprev, other);
  }
  float gval = gi[(size_t)b * 768 + tid];
  __syncthreads();

  for (int t = 0; t < 128; ++t) {
    float gnext = 0.f;
    if (t < 127) gnext = gi[(size_t)((t + 1) * 32 + b) * 768 + tid];

    float a0 = 0.f, a1 = 0.f, a2 = 0.f, a3 = 0.f;
    float a4 = 0.f, a5 = 0.f, a6 = 0.f, a7 = 0.f;
    #pragma unroll
    for (int k8 = 0; k8 < 16; ++k8) {
      uint4 ha = *(const uint4*)&h2[k8 * 8];
      uint4 hb = *(const uint4*)&h2[k8 * 8 + 4];
      a0 = dot2(w[k8 * 8 + 0], ha.x, a0);
      a1 = dot2(w[k8 * 8 + 1], ha.y, a1);
      a2 = dot2(w[k8 * 8 + 2], ha.z, a2);
      a3 = dot2(w[k8 * 8 + 3], ha.w, a3);
      a4 = dot2(w[k8 * 8 + 4], hb.x, a4);
      a5 = dot2(w[k8 * 8 + 5], hb.y, a5);
      a6 = dot2(w[k8 * 8 + 6], hb.z, a6);
      a7 = dot2(w[k8 * 8 + 7], hb.w, a7);
    }
    float gh = ((a0 + a1) + (a2 + a3)) + ((a4 + a5) + (a6 + a7)) + bj;

    if (role == 0)      r_sh[j] = sigmoid_fast(gval + gh);
    else if (role == 1) z_sh[j] = sigmoid_fast(gval + gh);
    __syncthreads();

    if (role == 2) {
      float r = r_sh[j];
      float z = z_sh[j];
      float n = tanh_fast(gval + r * gh);
      float hn = (1.f - z) * n + z * hprev;
      hprev = hn;
      hs[(size_t)(t * 32 + b) * 256 + j] = __float2bfloat16(hn);
      float other = __shfl_xor(hn, 1);
      if (!(j & 1)) h2[j >> 1] = pack_pair(hn, other);
    }
    gval = gnext;
    __syncthreads();
  }
}

// ---------- kernel 4: logits = hs @ W_out^T + b_out, bf16 MFMA ----------
// XOR-swizzled LDS + operand-swapped MFMA + NONTEMPORAL float4 stores.
__global__ __launch_bounds__(256) void logits_gemm(
    const __hip_bfloat16* __restrict__ A,   // hs (4096,256)
    const __hip_bfloat16* __restrict__ Bm,  // W_out bf16 (32000,256)
    const float* __restrict__ bout,         // (32000)
    float* __restrict__ out)                // (32,128,32000)
{
  __shared__ __hip_bfloat16 sA[128 * 64];
  __shared__ __hip_bfloat16 sB[128 * 64];
  int tid = threadIdx.x;
  int bid = blockIdx.x;                 // 0..7999
  int chunk = bid & 7;                  // XCD id (dispatch round-robin)
  int local = bid >> 3;
  int m0 = (chunk * 4 + (local & 3)) * 128;
  int n0 = (local >> 2) * 128;
  int lane = tid & 63;
  int wave = tid >> 6;
  int wm = (wave >> 1) * 64;
  int wn = (wave & 1) * 64;
  int srow = tid >> 3;
  int schunk = tid & 7;                 // 16B chunk 0..7 within row
  f32x4 acc[4][4] = {};

  for (int kt = 0; kt < 256; kt += 64) {
    #pragma unroll
    for (int it = 0; it < 4; ++it) {
      int row = it * 32 + srow;
      int gc = ((schunk ^ (row & 7)) * 8);     // pre-swizzled global chunk
      gll16(A  + (size_t)(m0 + row) * 256 + kt + gc, &sA[row * 64 + schunk * 8]);
      gll16(Bm + (size_t)(n0 + row) * 256 + kt + gc, &sB[row * 64 + schunk * 8]);
    }
    __syncthreads();
    #pragma unroll
    for (int kk = 0; kk < 2; ++kk) {
      bf16x8 af[4], bfr[4];
      #pragma unroll
      for (int m = 0; m < 4; ++m) {
        int r = wm + m * 16 + (lane & 15);
        int pc = ((kk * 4 + (lane >> 4)) ^ (r & 7)) * 8;
        af[m] = *(const bf16x8*)&sA[r * 64 + pc];
      }
      #pragma unroll
      for (int n = 0; n < 4; ++n) {
        int r = wn + n * 16 + (lane & 15);
        int pc = ((kk * 4 + (lane >> 4)) ^ (r & 7)) * 8;
        bfr[n] = *(const bf16x8*)&sB[r * 64 + pc];
      }
      #pragma unroll
      for (int m = 0; m < 4; ++m)
        #pragma unroll
        for (int n = 0; n < 4; ++n)
          acc[m][n] = __builtin_amdgcn_mfma_f32_16x16x32_bf16(bfr[n], af[m], acc[m][n], 0, 0, 0);
    }
    __syncthreads();
  }

  #pragma unroll
  for (int m = 0; m < 4; ++m) {
    int row = m0 + wm + m * 16 + (lane & 15);
    int t  = row >> 5;
    int bb = row & 31;
    float* orow = out + (size_t)(bb * 128 + t) * 32000;
    #pragma unroll
    for (int n = 0; n < 4; ++n) {
      int col0 = n0 + wn + n * 16 + (lane >> 4) * 4;
      f32x4 bv = *(const f32x4*)&bout[col0];
      f32x4 v = acc[m][n] + bv;
      __builtin_nontemporal_store(v, (f32x4*)&orow[col0]);
    }
  }
}

extern "C" void kernel_launch(void* const* d_in, const int* in_sizes, int n_in,
                              void* d_out, int out_size, void* d_ws, size_t ws_size,
                              hipStream_t stream) {
  const float* enc  = (const float*)d_in[0];
  const float* ench = (const float*)d_in[1];
  const int*   tgt  = (const int*)d_in[2];
  const float* embt = (const float*)d_in[3];
  const float* Wih  = (const float*)d_in[4];
  const float* Whh  = (const float*)d_in[5];
  const float* bih  = (const float*)d_in[6];
  const float* bhh  = (const float*)d_in[7];
  const float* Wout = (const float*)d_in[8];
  const float* bout = (const float*)d_in[9];
  float* out = (float*)d_out;

  char* ws = (char*)d_ws;
  float*          gi    = (float*)(ws);                          // 12,582,912 B
  __hip_bfloat16* hs    = (__hip_bfloat16*)(ws + 12582912);      //  2,097,152 B
  __hip_bfloat16* woutb = (__hip_bfloat16*)(ws + 14680064);      // 16,384,000 B
  uint32_t*       xh    = (uint32_t*)(ws + 31064064);            //  4,194,304 B
  uint32_t*       wihh  = (uint32_t*)(ws + 35258368);            //    786,432 B

  // Wp (128,768) u32 = 384 KB scratch in the TAIL of d_out: dead until
  // logits_gemm overwrites the whole output at the very end.
  uint32_t* Wp = (uint32_t*)(out + ((size_t)out_size - 98304));

  cvt_bf16_kernel<<<4000, 256, 0, stream>>>(Wout, (uint32_t*)woutb, V_ * H_);
  cvt_f16_kernel<<<384, 256, 0, stream>>>(Wih, wihh, 768 * 512);
  pack_whh<<<24, 256, 0, stream>>>(Whh, Wp);
  attn_kernel<<<dim3(32, 16), 256, 0, stream>>>(enc, tgt, embt, xh);
  gi_gemm_f16<<<dim3(6, 32), 256, 0, stream>>>((const _Float16*)xh, (const _Float16*)wihh, bih, gi);
  gru_kernel<<<32, 768, 0, stream>>>(gi, Wp, bhh, ench, hs);
  logits_gemm<<<8000, 256, 0, stream>>>(hs, woutb, bout, out);
}